// Round 4
// baseline (130.234 us; speedup 1.0000x reference)
//
#include <hip/hip_runtime.h>
#include <hip/hip_bf16.h>
#include <stdint.h>

#define B_ROWS 8192
#define DIM 256
#define JCHUNK 512
#define WPB 4   // waves per block
#define ROWS_PER_WAVE 64
#define ROWS_PER_BLOCK (WPB * ROWS_PER_WAVE)  // 256
#define NT2 (JCHUNK / 32)                     // 16 phases of 32 j-cols per block
#define NTILES 4                              // A row-tiles per wave (64 rows)

typedef __bf16 bf16x8 __attribute__((ext_vector_type(8)));
typedef float f32x4 __attribute__((ext_vector_type(4)));

#if __has_builtin(__builtin_amdgcn_exp2f)
#define EXP2F(x) __builtin_amdgcn_exp2f(x)
#else
#define EXP2F(x) exp2f(x)
#endif

__device__ __forceinline__ unsigned short f2bf_rne(float f) {
    unsigned int u = __builtin_bit_cast(unsigned int, f);
    unsigned int r = (u + 0x7FFFu + ((u >> 16) & 1u)) >> 16;
    return (unsigned short)r;
}

// swizzled LDS tile: 32 rows x 512B; chunk c (16B) of row r at r*512 + ((c^r)&31)*16
__device__ __forceinline__ void stw(unsigned char* buf, int r, int c, uint4 v) {
    *reinterpret_cast<uint4*>(&buf[r * 512 + ((c ^ r) & 31) * 16]) = v;
}

// ---------------- Kernel 1: L2-normalize rows -> bf16, plus zero accumulators ----------------
__global__ __launch_bounds__(256) void normalize_k(const float* __restrict__ emb,
                                                   unsigned short* __restrict__ ebf,
                                                   float* __restrict__ Sall) {  // 2*8192 floats
    const int idx = blockIdx.x * 256 + threadIdx.x;
    if (idx < 4096) {
        float4 z = {0.f, 0.f, 0.f, 0.f};
        reinterpret_cast<float4*>(Sall)[idx] = z;
    }
    const int row = blockIdx.x * 4 + (threadIdx.x >> 6);
    const int lane = threadIdx.x & 63;  // 4 floats each covers DIM=256
    const float4 v = reinterpret_cast<const float4*>(emb + (size_t)row * DIM)[lane];
    float ss = v.x * v.x + v.y * v.y + v.z * v.z + v.w * v.w;
    #pragma unroll
    for (int off = 32; off; off >>= 1) ss += __shfl_xor(ss, off);
    const float scale = 1.0f / fmaxf(sqrtf(ss), 1e-12f);
    ushort4 o;
    o.x = f2bf_rne(v.x * scale);
    o.y = f2bf_rne(v.y * scale);
    o.z = f2bf_rne(v.z * scale);
    o.w = f2bf_rne(v.w * scale);
    reinterpret_cast<ushort4*>(ebf + (size_t)row * DIM)[lane] = o;
}

// ---------------- Kernel 2: fused sim + masked exp-sum ----------------
// 64 rows/wave (4 A-tiles register/AGPR-resident, K=256) at 2 waves/SIMD — the
// register-optimal shape (R1/R2 showed both less A-residency and forced higher
// occupancy regress). Loss there is per-phase barrier overhead, so this version
// processes 32 j-cols per phase (16 KB LDS tile, two 16-col MFMA sub-tiles),
// halving barriers 32 -> 16. Staging is split so only 2 uint4 are in flight at
// once (same register liveness as the 51 us baseline):
//   load p0,p1 | compute g=0 | store p0,p1 + load p2,p3 | compute g=1 | store p2,p3 | barrier
__global__ __launch_bounds__(256, 2) void sim_k(const unsigned short* __restrict__ ebf,
                                                const int* __restrict__ labels,
                                                float* __restrict__ Sall,
                                                float* __restrict__ Spos) {
    // exp((dot-1)/T) = exp2((dot-1) * INV_T*log2e)
    constexpr float K2 = 14.285714285714286f * 1.4426950408889634f;  // 20.60993
    __shared__ __align__(16) unsigned char lds0[16384];
    __shared__ __align__(16) unsigned char lds1[16384];
    __shared__ int lds_lab[JCHUNK];

    const int tid  = threadIdx.x;
    const int wave = tid >> 6;
    const int lane = tid & 63;
    const int col  = lane & 15;
    const int quad = lane >> 4;

    const int rowblk = blockIdx.x >> 4;            // 0..31
    const int jblk   = blockIdx.x & 15;            // 0..15
    const int i_base = rowblk * ROWS_PER_BLOCK + wave * ROWS_PER_WAVE;
    const int j0     = jblk * JCHUNK;

    // ---- Preload A-fragments (4 tiles x 8 K-steps) + row labels ----
    // lane L holds A[row = L&15][k = kk*32 + (L>>4)*8 + 0..7]
    bf16x8 afrag[NTILES][8];
    int li[NTILES][4];
    #pragma unroll
    for (int t = 0; t < NTILES; ++t) {
        const int arow = i_base + t * 16 + col;
        const uint4* ap = reinterpret_cast<const uint4*>(ebf) + (size_t)arow * 32 + quad;
        #pragma unroll
        for (int kk = 0; kk < 8; ++kk)
            afrag[t][kk] = __builtin_bit_cast(bf16x8, ap[kk * 4]);
        #pragma unroll
        for (int r = 0; r < 4; ++r)
            li[t][r] = labels[i_base + t * 16 + quad * 4 + r];
    }

    const int st_r = tid >> 5;      // 0..7
    const int st_c = tid & 31;
    const uint4* gB = reinterpret_cast<const uint4*>(ebf);

    // ---- Prologue: stage 32-row tile 0 into lds0; labels -> LDS ----
    lds_lab[tid] = labels[j0 + tid];
    lds_lab[256 + tid] = labels[j0 + 256 + tid];
    #pragma unroll
    for (int h = 0; h < 4; ++h) {
        const uint4 v = gB[(size_t)(j0 + h * 8 + st_r) * 32 + st_c];
        stw(lds0, h * 8 + st_r, st_c, v);
    }
    __syncthreads();

    float s_all[NTILES][4] = {};
    float s_pos[NTILES][4] = {};

    for (int jt = 0; jt < NT2; ++jt) {
        unsigned char* ldsR = (jt & 1) ? lds1 : lds0;
        unsigned char* ldsW = (jt & 1) ? lds0 : lds1;
        const bool havenext = (jt + 1) < NT2;
        const int jn = j0 + (jt + 1) * 32;

        // first half of next tile's loads (rows 0..15)
        uint4 p0, p1, p2, p3;
        if (havenext) {
            p0 = gB[(size_t)(jn + st_r) * 32 + st_c];
            p1 = gB[(size_t)(jn + 8 + st_r) * 32 + st_c];
        }

        #pragma unroll
        for (int g = 0; g < 2; ++g) {
            f32x4 acc[NTILES];
            #pragma unroll
            for (int t = 0; t < NTILES; ++t) acc[t] = (f32x4){0.f, 0.f, 0.f, 0.f};
            #pragma unroll
            for (int kk = 0; kk < 8; ++kk) {
                const int R = g * 16 + col;
                const int c = kk * 4 + quad;
                const bf16x8 bfrag = *reinterpret_cast<const bf16x8*>(
                    &ldsR[R * 512 + ((c ^ R) & 31) * 16]);
                #pragma unroll
                for (int t = 0; t < NTILES; ++t)
                    acc[t] = __builtin_amdgcn_mfma_f32_16x16x32_bf16(afrag[t][kk], bfrag, acc[t], 0, 0, 0);
            }

            const int jcol = j0 + jt * 32 + g * 16 + col;
            const int lj = lds_lab[jt * 32 + g * 16 + col];

            // Epilogue. D[row = quad*4+r][col]. Diagonal only possible when this
            // 16-col strip overlaps the wave's 64-row strip (wave-uniform branch).
            const int strip = j0 + jt * 32 + g * 16;
            const bool diag_possible = (strip < i_base + ROWS_PER_WAVE) && (i_base < strip + 16);
            if (!diag_possible) {
                #pragma unroll
                for (int t = 0; t < NTILES; ++t) {
                    #pragma unroll
                    for (int r = 0; r < 4; ++r) {
                        const float ex = EXP2F(fmaf(acc[t][r], K2, -K2));
                        s_all[t][r] += ex;
                        s_pos[t][r] += (lj == li[t][r]) ? ex : 0.0f;
                    }
                }
            } else {
                #pragma unroll
                for (int t = 0; t < NTILES; ++t) {
                    #pragma unroll
                    for (int r = 0; r < 4; ++r) {
                        const int irow = i_base + t * 16 + quad * 4 + r;
                        const float ex = EXP2F(fmaf(acc[t][r], K2, -K2));
                        const bool valid = (jcol != irow);
                        const bool pos = valid && (lj == li[t][r]);
                        s_all[t][r] += valid ? ex : 0.0f;
                        s_pos[t][r] += pos ? ex : 0.0f;
                    }
                }
            }

            // staged write/load interleave: keeps only 2 uint4 live at any time,
            // and each load is covered by a full sub-tile of MFMA before its store.
            if (havenext) {
                if (g == 0) {
                    stw(ldsW, st_r, st_c, p0);
                    stw(ldsW, st_r + 8, st_c, p1);
                    p2 = gB[(size_t)(jn + 16 + st_r) * 32 + st_c];
                    p3 = gB[(size_t)(jn + 24 + st_r) * 32 + st_c];
                } else {
                    stw(ldsW, st_r + 16, st_c, p2);
                    stw(ldsW, st_r + 24, st_c, p3);
                }
            }
        }
        __syncthreads();
    }

    // Reduce over the 16 column-lanes within each quad, then one atomic per row.
    #pragma unroll
    for (int t = 0; t < NTILES; ++t) {
        #pragma unroll
        for (int r = 0; r < 4; ++r) {
            float a = s_all[t][r];
            float pp = s_pos[t][r];
            #pragma unroll
            for (int off = 1; off < 16; off <<= 1) {
                a += __shfl_xor(a, off);
                pp += __shfl_xor(pp, off);
            }
            if (col == 0) {
                const int irow = i_base + t * 16 + quad * 4 + r;
                atomicAdd(&Sall[irow], a);
                atomicAdd(&Spos[irow], pp);
            }
        }
    }
}

// ---------------- Kernel 3: per-row loss + mean ----------------
__global__ __launch_bounds__(1024) void finalize_k(const float* __restrict__ Sall,
                                                   const float* __restrict__ Spos,
                                                   float* __restrict__ out) {
    const int tid = threadIdx.x;
    float sum = 0.0f;
    int cnt = 0;
    #pragma unroll
    for (int k = 0; k < B_ROWS / 1024; ++k) {
        const int i = k * 1024 + tid;
        const float sp = Spos[i];
        const float sa = Sall[i];
        if (sp > 0.0f) {
            sum += __logf(__fdividef(sa, sp));  // log(sa)-log(sp); fixed max M cancels
            ++cnt;
        }
    }
    #pragma unroll
    for (int off = 32; off; off >>= 1) {
        sum += __shfl_xor(sum, off);
        cnt += __shfl_xor(cnt, off);
    }
    __shared__ float ssum[16];
    __shared__ int scnt[16];
    const int wave = tid >> 6, lane = tid & 63;
    if (lane == 0) { ssum[wave] = sum; scnt[wave] = cnt; }
    __syncthreads();
    if (tid == 0) {
        float s = 0.0f;
        int c = 0;
        #pragma unroll
        for (int w = 0; w < 16; ++w) { s += ssum[w]; c += scnt[w]; }
        out[0] = (c > 0) ? s / (float)c : 0.0f;
    }
}

extern "C" void kernel_launch(void* const* d_in, const int* in_sizes, int n_in,
                              void* d_out, int out_size, void* d_ws, size_t ws_size,
                              hipStream_t stream) {
    const float* emb   = (const float*)d_in[0];
    const int* labels  = (const int*)d_in[1];
    float* out         = (float*)d_out;

    unsigned short* ebf = (unsigned short*)d_ws;                       // 4 MB bf16 normalized
    float* Sall = (float*)((char*)d_ws + (size_t)B_ROWS * DIM * 2);    // 32 KB
    float* Spos = Sall + B_ROWS;                                       // 32 KB

    normalize_k<<<B_ROWS / 4, 256, 0, stream>>>(emb, ebf, Sall);

    dim3 grid((B_ROWS / ROWS_PER_BLOCK) * (B_ROWS / JCHUNK));          // 32*16 = 512
    sim_k<<<grid, 256, 0, stream>>>(ebf, labels, Sall, Spos);

    finalize_k<<<1, 1024, 0, stream>>>(Sall, Spos, out);
}

// Round 5
// 124.023 us; speedup vs baseline: 1.0501x; 1.0501x over previous
//
#include <hip/hip_runtime.h>
#include <hip/hip_bf16.h>
#include <stdint.h>

#define B_ROWS 8192
#define DIM 256
#define JCHUNK 512
#define WPB 4   // waves per block
#define ROWS_PER_WAVE 64
#define ROWS_PER_BLOCK (WPB * ROWS_PER_WAVE)  // 256
#define NT (JCHUNK / 16)                      // 32 j-tiles per block
#define NTILES 4                              // A row-tiles per wave (64 rows)

typedef __bf16 bf16x8 __attribute__((ext_vector_type(8)));
typedef float f32x4 __attribute__((ext_vector_type(4)));

#if __has_builtin(__builtin_amdgcn_exp2f)
#define EXP2F(x) __builtin_amdgcn_exp2f(x)
#else
#define EXP2F(x) exp2f(x)
#endif

__device__ __forceinline__ unsigned short f2bf_rne(float f) {
    unsigned int u = __builtin_bit_cast(unsigned int, f);
    unsigned int r = (u + 0x7FFFu + ((u >> 16) & 1u)) >> 16;
    return (unsigned short)r;
}

// async global->LDS, 16B per lane; LDS dest is wave-uniform base + lane*16 (linear)
__device__ __forceinline__ void gld_lds16(const void* g, void* l) {
    __builtin_amdgcn_global_load_lds(
        (const __attribute__((address_space(1))) unsigned int*)g,
        (__attribute__((address_space(3))) unsigned int*)l, 16, 0, 0);
}

// ---------------- Kernel 1: L2-normalize rows -> bf16, plus zero accumulators ----------------
__global__ __launch_bounds__(256) void normalize_k(const float* __restrict__ emb,
                                                   unsigned short* __restrict__ ebf,
                                                   float* __restrict__ Sall) {  // 2*8192 floats
    const int idx = blockIdx.x * 256 + threadIdx.x;
    if (idx < 4096) {
        float4 z = {0.f, 0.f, 0.f, 0.f};
        reinterpret_cast<float4*>(Sall)[idx] = z;
    }
    const int row = blockIdx.x * 4 + (threadIdx.x >> 6);
    const int lane = threadIdx.x & 63;  // 4 floats each covers DIM=256
    const float4 v = reinterpret_cast<const float4*>(emb + (size_t)row * DIM)[lane];
    float ss = v.x * v.x + v.y * v.y + v.z * v.z + v.w * v.w;
    #pragma unroll
    for (int off = 32; off; off >>= 1) ss += __shfl_xor(ss, off);
    const float scale = 1.0f / fmaxf(sqrtf(ss), 1e-12f);
    ushort4 o;
    o.x = f2bf_rne(v.x * scale);
    o.y = f2bf_rne(v.y * scale);
    o.z = f2bf_rne(v.z * scale);
    o.w = f2bf_rne(v.w * scale);
    reinterpret_cast<ushort4*>(ebf + (size_t)row * DIM)[lane] = o;
}

// ---------------- Kernel 2: fused sim + masked exp-sum, ZERO-BARRIER ----------------
// 64 rows/wave (4 A-tiles register/AGPR-resident, K=256), 2 waves/SIMD (register-
// optimal; R1/R2/R4 showed any deviation regresses). The 51us baseline's loss was
// the per-tile block-wide __syncthreads + full drain (lockstep stall, ~1450cyc/iter).
// Here each wave owns a PRIVATE double-buffered LDS tile (4 waves x 2 x 8KB = 64KB)
// filled via global_load_lds (no staging registers -> no R4-style spill) and
// self-synchronizes with counted s_waitcnt vmcnt(8): the freshly issued 8 prefetch
// loads stay in flight across the wait (T4). XOR bank-swizzle is preserved by
// pre-swizzling the per-lane GLOBAL source address (LDS dest stays linear, m173
// pattern); the ds_read side is byte-identical to the measured-0-conflict layout.
// No __syncthreads anywhere: waves drift and mutually hide latency on the SIMD.
__global__ __launch_bounds__(256, 2) void sim_k(const unsigned short* __restrict__ ebf,
                                                const int* __restrict__ labels,
                                                float* __restrict__ Sall,
                                                float* __restrict__ Spos) {
    // exp((dot-1)/T) = exp2((dot-1) * INV_T*log2e)
    constexpr float K2 = 14.285714285714286f * 1.4426950408889634f;  // 20.60993
    __shared__ __align__(16) unsigned char bufs[WPB][2][8192];       // 64 KB exactly

    const int tid  = threadIdx.x;
    const int wave = tid >> 6;
    const int lane = tid & 63;
    const int col  = lane & 15;
    const int quad = lane >> 4;

    const int rowblk = blockIdx.x >> 4;            // 0..31
    const int jblk   = blockIdx.x & 15;            // 0..15
    const int i_base = rowblk * ROWS_PER_BLOCK + wave * ROWS_PER_WAVE;
    const int j0     = jblk * JCHUNK;

    // ---- Preload A-fragments (4 tiles x 8 K-steps) + row labels ----
    // lane L holds A[row = L&15][k = kk*32 + (L>>4)*8 + 0..7]
    bf16x8 afrag[NTILES][8];
    int li[NTILES][4];
    #pragma unroll
    for (int t = 0; t < NTILES; ++t) {
        const int arow = i_base + t * 16 + col;
        const uint4* ap = reinterpret_cast<const uint4*>(ebf) + (size_t)arow * 32 + quad;
        #pragma unroll
        for (int kk = 0; kk < 8; ++kk)
            afrag[t][kk] = __builtin_bit_cast(bf16x8, ap[kk * 4]);
        #pragma unroll
        for (int r = 0; r < 4; ++r)
            li[t][r] = labels[i_base + t * 16 + quad * 4 + r];
    }

    // ---- Per-lane pre-swizzled global source offsets for staging ----
    // Instruction i writes LDS bytes [i*1024, i*1024+1024): lane l -> linear slot
    // row r = i*2 + (l>>5), chunk slot s = l&31. To reproduce the XOR layout
    // (slot s of row r holds global chunk s^r), lane l fetches global chunk
    // c = (l&31) ^ r of row r.
    const int lo = lane & 31, hi = lane >> 5;
    int voff[8];
    #pragma unroll
    for (int i = 0; i < 8; ++i) {
        const int r = i * 2 + hi;                  // row within 16-row tile
        voff[i] = r * 512 + ((lo ^ r) & 31) * 16;  // bytes
    }

    const char* gBase = reinterpret_cast<const char*>(ebf) + (size_t)j0 * 512;
    unsigned char* wb[2] = { bufs[wave][0], bufs[wave][1] };

    // ---- Prologue: issue tile 0 into buffer 0 (no barrier needed: buffers private)
    #pragma unroll
    for (int i = 0; i < 8; ++i)
        gld_lds16(gBase + voff[i], wb[0] + i * 1024);

    float s_all[NTILES][4] = {};
    float s_pos[NTILES][4] = {};

    for (int jt = 0; jt < NT; ++jt) {
        unsigned char* bufR = wb[jt & 1];
        // this tile's column label (L2-hot 64B segment; participates in the vmcnt
        // discipline: current tile's 8 stages are strictly the OLDEST outstanding,
        // so drain-to-8 always completes them; compiler adds its own precise wait
        // for lj's register dependency)
        const int lj = labels[j0 + jt * 16 + col];

        const bool havenext = (jt + 1) < NT;
        if (havenext) {
            const char* gT = gBase + (size_t)(jt + 1) * 8192;
            unsigned char* bufW = wb[(jt + 1) & 1];
            #pragma unroll
            for (int i = 0; i < 8; ++i)
                gld_lds16(gT + voff[i], bufW + i * 1024);
            asm volatile("s_waitcnt vmcnt(8)" ::: "memory");   // tile jt ready; 8 prefetch stay in flight
        } else {
            asm volatile("s_waitcnt vmcnt(0)" ::: "memory");   // last tile: drain all
        }

        // MFMA: read each B-fragment (swizzled, conflict-free) then feed 4 row-tiles
        f32x4 acc[NTILES];
        #pragma unroll
        for (int t = 0; t < NTILES; ++t) acc[t] = (f32x4){0.f, 0.f, 0.f, 0.f};
        __builtin_amdgcn_s_setprio(1);
        #pragma unroll
        for (int kk = 0; kk < 8; ++kk) {
            const int c = kk * 4 + quad;
            const bf16x8 bfrag = *reinterpret_cast<const bf16x8*>(
                &bufR[col * 512 + ((c ^ col) & 31) * 16]);
            #pragma unroll
            for (int t = 0; t < NTILES; ++t)
                acc[t] = __builtin_amdgcn_mfma_f32_16x16x32_bf16(afrag[t][kk], bfrag, acc[t], 0, 0, 0);
        }
        __builtin_amdgcn_s_setprio(0);

        const int jcol = j0 + jt * 16 + col;

        // Epilogue. D[row = quad*4+r][col]. Diagonal only possible when this 16-col
        // strip overlaps the wave's 64-row strip (wave-uniform branch).
        const int jt16 = j0 + jt * 16;
        const bool diag_possible = (jt16 < i_base + ROWS_PER_WAVE) && (i_base < jt16 + 16);
        if (!diag_possible) {
            #pragma unroll
            for (int t = 0; t < NTILES; ++t) {
                #pragma unroll
                for (int r = 0; r < 4; ++r) {
                    const float ex = EXP2F(fmaf(acc[t][r], K2, -K2));
                    s_all[t][r] += ex;
                    s_pos[t][r] += (lj == li[t][r]) ? ex : 0.0f;
                }
            }
        } else {
            #pragma unroll
            for (int t = 0; t < NTILES; ++t) {
                #pragma unroll
                for (int r = 0; r < 4; ++r) {
                    const int irow = i_base + t * 16 + quad * 4 + r;
                    const float ex = EXP2F(fmaf(acc[t][r], K2, -K2));
                    const bool valid = (jcol != irow);
                    const bool pos = valid && (lj == li[t][r]);
                    s_all[t][r] += valid ? ex : 0.0f;
                    s_pos[t][r] += pos ? ex : 0.0f;
                }
            }
        }
    }

    // Reduce over the 16 column-lanes within each quad, then one atomic per row.
    #pragma unroll
    for (int t = 0; t < NTILES; ++t) {
        #pragma unroll
        for (int r = 0; r < 4; ++r) {
            float a = s_all[t][r];
            float pp = s_pos[t][r];
            #pragma unroll
            for (int off = 1; off < 16; off <<= 1) {
                a += __shfl_xor(a, off);
                pp += __shfl_xor(pp, off);
            }
            if (col == 0) {
                const int irow = i_base + t * 16 + quad * 4 + r;
                atomicAdd(&Sall[irow], a);
                atomicAdd(&Spos[irow], pp);
            }
        }
    }
}

// ---------------- Kernel 3: per-row loss + mean ----------------
__global__ __launch_bounds__(1024) void finalize_k(const float* __restrict__ Sall,
                                                   const float* __restrict__ Spos,
                                                   float* __restrict__ out) {
    const int tid = threadIdx.x;
    float sum = 0.0f;
    int cnt = 0;
    #pragma unroll
    for (int k = 0; k < B_ROWS / 1024; ++k) {
        const int i = k * 1024 + tid;
        const float sp = Spos[i];
        const float sa = Sall[i];
        if (sp > 0.0f) {
            sum += __logf(__fdividef(sa, sp));  // log(sa)-log(sp); fixed max M cancels
            ++cnt;
        }
    }
    #pragma unroll
    for (int off = 32; off; off >>= 1) {
        sum += __shfl_xor(sum, off);
        cnt += __shfl_xor(cnt, off);
    }
    __shared__ float ssum[16];
    __shared__ int scnt[16];
    const int wave = tid >> 6, lane = tid & 63;
    if (lane == 0) { ssum[wave] = sum; scnt[wave] = cnt; }
    __syncthreads();
    if (tid == 0) {
        float s = 0.0f;
        int c = 0;
        #pragma unroll
        for (int w = 0; w < 16; ++w) { s += ssum[w]; c += scnt[w]; }
        out[0] = (c > 0) ? s / (float)c : 0.0f;
    }
}

extern "C" void kernel_launch(void* const* d_in, const int* in_sizes, int n_in,
                              void* d_out, int out_size, void* d_ws, size_t ws_size,
                              hipStream_t stream) {
    const float* emb   = (const float*)d_in[0];
    const int* labels  = (const int*)d_in[1];
    float* out         = (float*)d_out;

    unsigned short* ebf = (unsigned short*)d_ws;                       // 4 MB bf16 normalized
    float* Sall = (float*)((char*)d_ws + (size_t)B_ROWS * DIM * 2);    // 32 KB
    float* Spos = Sall + B_ROWS;                                       // 32 KB

    normalize_k<<<B_ROWS / 4, 256, 0, stream>>>(emb, ebf, Sall);

    dim3 grid((B_ROWS / ROWS_PER_BLOCK) * (B_ROWS / JCHUNK));          // 32*16 = 512
    sim_k<<<grid, 256, 0, stream>>>(ebf, labels, Sall, Spos);

    finalize_k<<<1, 1024, 0, stream>>>(Sall, Spos, out);
}

// Round 6
// 112.347 us; speedup vs baseline: 1.1592x; 1.1039x over previous
//
#include <hip/hip_runtime.h>
#include <hip/hip_bf16.h>
#include <stdint.h>

#define B_ROWS 8192
#define DIM 256
#define JCHUNK 512
#define WPB 4   // waves per block
#define ROWS_PER_WAVE 64
#define ROWS_PER_BLOCK (WPB * ROWS_PER_WAVE)  // 256
#define NT (JCHUNK / 16)                      // 32 j-tiles per block
#define NTILES 4                              // A row-tiles per wave (64 rows)

typedef __bf16 bf16x8 __attribute__((ext_vector_type(8)));
typedef float f32x4 __attribute__((ext_vector_type(4)));

#if __has_builtin(__builtin_amdgcn_exp2f)
#define EXP2F(x) __builtin_amdgcn_exp2f(x)
#else
#define EXP2F(x) exp2f(x)
#endif

__device__ __forceinline__ unsigned short f2bf_rne(float f) {
    unsigned int u = __builtin_bit_cast(unsigned int, f);
    unsigned int r = (u + 0x7FFFu + ((u >> 16) & 1u)) >> 16;
    return (unsigned short)r;
}

// async global->LDS, 16B per lane; LDS dest is wave-uniform base + lane*16 (linear)
__device__ __forceinline__ void gld_lds16(const void* g, void* l) {
    __builtin_amdgcn_global_load_lds(
        (const __attribute__((address_space(1))) unsigned int*)g,
        (__attribute__((address_space(3))) unsigned int*)l, 16, 0, 0);
}

// ---------------- Kernel 1: L2-normalize rows -> bf16, plus zero accumulators ----------------
__global__ __launch_bounds__(256) void normalize_k(const float* __restrict__ emb,
                                                   unsigned short* __restrict__ ebf,
                                                   float* __restrict__ Sall) {  // 2*8192 floats
    const int idx = blockIdx.x * 256 + threadIdx.x;
    if (idx < 4096) {
        float4 z = {0.f, 0.f, 0.f, 0.f};
        reinterpret_cast<float4*>(Sall)[idx] = z;
    }
    const int row = blockIdx.x * 4 + (threadIdx.x >> 6);
    const int lane = threadIdx.x & 63;  // 4 floats each covers DIM=256
    const float4 v = reinterpret_cast<const float4*>(emb + (size_t)row * DIM)[lane];
    float ss = v.x * v.x + v.y * v.y + v.z * v.z + v.w * v.w;
    #pragma unroll
    for (int off = 32; off; off >>= 1) ss += __shfl_xor(ss, off);
    const float scale = 1.0f / fmaxf(sqrtf(ss), 1e-12f);
    ushort4 o;
    o.x = f2bf_rne(v.x * scale);
    o.y = f2bf_rne(v.y * scale);
    o.z = f2bf_rne(v.z * scale);
    o.w = f2bf_rne(v.w * scale);
    reinterpret_cast<ushort4*>(ebf + (size_t)row * DIM)[lane] = o;
}

// ---------------- Kernel 2: fused sim + masked exp-sum ----------------
// 64 rows/wave (4 A-tiles register/AGPR-resident, K=256), 2 waves/SIMD.
// Synthesis of rounds 0-5:
//  - COOPERATIVE staging (1x L2 traffic; R5's private staging was 4x) of the
//    shared 8KB j-tile via global_load_lds (0 staging registers; R2/R4 spilled).
//  - Labels LDS-resident (R5's per-iter global label load serialized L2 latency).
//  - RAW s_barrier + counted s_waitcnt vmcnt(2): prefetch stays in flight across
//    the barrier, removing __syncthreads' full vmcnt/lgkm drain (the ~40%
//    lockstep stall of the 51us baseline).
//  - TRIPLE buffer (3 x 8KB): with one barrier/iter waves may skew one read
//    phase, so LDS reuse distance 3 is required (reuse-2 races, reuse-3 proven
//    safe by barrier-arrival analysis).
//  - XOR bank-swizzle preserved by pre-swizzling the per-lane GLOBAL source
//    address (LDS dest linear, m173 pattern); ds_read side byte-identical to
//    the measured-0-conflict layout.
__global__ __launch_bounds__(256, 2) void sim_k(const unsigned short* __restrict__ ebf,
                                                const int* __restrict__ labels,
                                                float* __restrict__ Sall,
                                                float* __restrict__ Spos) {
    // exp((dot-1)/T) = exp2((dot-1) * INV_T*log2e)
    constexpr float K2 = 14.285714285714286f * 1.4426950408889634f;  // 20.60993
    __shared__ __align__(16) unsigned char bufs[3][8192];            // 24 KB
    __shared__ int lds_lab[JCHUNK];

    const int tid  = threadIdx.x;
    const int wave = tid >> 6;
    const int lane = tid & 63;
    const int col  = lane & 15;
    const int quad = lane >> 4;

    const int rowblk = blockIdx.x >> 4;            // 0..31
    const int jblk   = blockIdx.x & 15;            // 0..15
    const int i_base = rowblk * ROWS_PER_BLOCK + wave * ROWS_PER_WAVE;
    const int j0     = jblk * JCHUNK;

    // ---- Preload A-fragments (4 tiles x 8 K-steps) + row labels ----
    // lane L holds A[row = L&15][k = kk*32 + (L>>4)*8 + 0..7]
    bf16x8 afrag[NTILES][8];
    int li[NTILES][4];
    #pragma unroll
    for (int t = 0; t < NTILES; ++t) {
        const int arow = i_base + t * 16 + col;
        const uint4* ap = reinterpret_cast<const uint4*>(ebf) + (size_t)arow * 32 + quad;
        #pragma unroll
        for (int kk = 0; kk < 8; ++kk)
            afrag[t][kk] = __builtin_bit_cast(bf16x8, ap[kk * 4]);
        #pragma unroll
        for (int r = 0; r < 4; ++r)
            li[t][r] = labels[i_base + t * 16 + quad * 4 + r];
    }

    // ---- Per-lane pre-swizzled global source offsets ----
    // Wave w stages LDS bytes [2w*1024, (2w+2)*1024) of the shared tile, i.e.
    // rows r = 4w + 2g + (lane>>5), g in {0,1}; lane slot s = lane&31. To land
    // the XOR layout (slot s of row r holds global chunk s^r) with a LINEAR LDS
    // destination, the lane fetches global chunk (s^r)&31 of row r.
    const int lo = lane & 31, hi = lane >> 5;
    int voff[2];
    #pragma unroll
    for (int g = 0; g < 2; ++g) {
        const int r = 4 * wave + 2 * g + hi;
        voff[g] = r * 512 + ((lo ^ r) & 31) * 16;  // bytes within the 8KB tile
    }
    const int ldst0 = (2 * wave) * 1024;           // this wave's LDS chunk base

    const char* gBase = reinterpret_cast<const char*>(ebf) + (size_t)j0 * 512;

    // ---- Prologue: labels -> LDS; stage tile 0 into bufs[0]; one full sync ----
    lds_lab[tid] = labels[j0 + tid];
    lds_lab[256 + tid] = labels[j0 + 256 + tid];
    gld_lds16(gBase + voff[0], bufs[0] + ldst0);
    gld_lds16(gBase + voff[1], bufs[0] + ldst0 + 1024);
    __syncthreads();   // drains prologue staging + lds_lab (once)

    float s_all[NTILES][4] = {};
    float s_pos[NTILES][4] = {};

    unsigned char* bR = bufs[0];
    unsigned char* bN1 = bufs[1];
    unsigned char* bN2 = bufs[2];

    for (int jt = 0; jt < NT; ++jt) {
        // issue next tile's stage into the buffer 1 ahead; tile jt's stages
        // (issued last iter) become the oldest outstanding vmem ops.
        if ((jt + 1) < NT) {
            const char* gT = gBase + (size_t)(jt + 1) * 8192;
            gld_lds16(gT + voff[0], bN1 + ldst0);
            gld_lds16(gT + voff[1], bN1 + ldst0 + 1024);
            asm volatile("s_waitcnt vmcnt(2)" ::: "memory");  // tile jt landed; 2 prefetch in flight
        } else {
            asm volatile("s_waitcnt vmcnt(0)" ::: "memory");  // last tile: drain
        }
        __builtin_amdgcn_s_barrier();          // raw barrier: NO vmcnt drain
        __builtin_amdgcn_sched_barrier(0);     // fence: no ds_read hoisted above

        // MFMA: read each B-fragment (swizzled, conflict-free) then feed 4 row-tiles
        f32x4 acc[NTILES];
        #pragma unroll
        for (int t = 0; t < NTILES; ++t) acc[t] = (f32x4){0.f, 0.f, 0.f, 0.f};
        __builtin_amdgcn_s_setprio(1);
        #pragma unroll
        for (int kk = 0; kk < 8; ++kk) {
            const int c = kk * 4 + quad;
            const bf16x8 bfrag = *reinterpret_cast<const bf16x8*>(
                &bR[col * 512 + ((c ^ col) & 31) * 16]);
            #pragma unroll
            for (int t = 0; t < NTILES; ++t)
                acc[t] = __builtin_amdgcn_mfma_f32_16x16x32_bf16(afrag[t][kk], bfrag, acc[t], 0, 0, 0);
        }
        __builtin_amdgcn_s_setprio(0);

        const int jcol = j0 + jt * 16 + col;
        const int lj = lds_lab[jt * 16 + col];

        // Epilogue. D[row = quad*4+r][col]. Diagonal only possible when this 16-col
        // strip overlaps the wave's 64-row strip (wave-uniform branch).
        const int jt16 = j0 + jt * 16;
        const bool diag_possible = (jt16 < i_base + ROWS_PER_WAVE) && (i_base < jt16 + 16);
        if (!diag_possible) {
            #pragma unroll
            for (int t = 0; t < NTILES; ++t) {
                #pragma unroll
                for (int r = 0; r < 4; ++r) {
                    const float ex = EXP2F(fmaf(acc[t][r], K2, -K2));
                    s_all[t][r] += ex;
                    s_pos[t][r] += (lj == li[t][r]) ? ex : 0.0f;
                }
            }
        } else {
            #pragma unroll
            for (int t = 0; t < NTILES; ++t) {
                #pragma unroll
                for (int r = 0; r < 4; ++r) {
                    const int irow = i_base + t * 16 + quad * 4 + r;
                    const float ex = EXP2F(fmaf(acc[t][r], K2, -K2));
                    const bool valid = (jcol != irow);
                    const bool pos = valid && (lj == li[t][r]);
                    s_all[t][r] += valid ? ex : 0.0f;
                    s_pos[t][r] += pos ? ex : 0.0f;
                }
            }
        }

        // rotate triple buffer
        unsigned char* tmp = bR;
        bR = bN1; bN1 = bN2; bN2 = tmp;
    }

    // Reduce over the 16 column-lanes within each quad, then one atomic per row.
    #pragma unroll
    for (int t = 0; t < NTILES; ++t) {
        #pragma unroll
        for (int r = 0; r < 4; ++r) {
            float a = s_all[t][r];
            float pp = s_pos[t][r];
            #pragma unroll
            for (int off = 1; off < 16; off <<= 1) {
                a += __shfl_xor(a, off);
                pp += __shfl_xor(pp, off);
            }
            if (col == 0) {
                const int irow = i_base + t * 16 + quad * 4 + r;
                atomicAdd(&Sall[irow], a);
                atomicAdd(&Spos[irow], pp);
            }
        }
    }
}

// ---------------- Kernel 3: per-row loss + mean ----------------
__global__ __launch_bounds__(1024) void finalize_k(const float* __restrict__ Sall,
                                                   const float* __restrict__ Spos,
                                                   float* __restrict__ out) {
    const int tid = threadIdx.x;
    float sum = 0.0f;
    int cnt = 0;
    #pragma unroll
    for (int k = 0; k < B_ROWS / 1024; ++k) {
        const int i = k * 1024 + tid;
        const float sp = Spos[i];
        const float sa = Sall[i];
        if (sp > 0.0f) {
            sum += __logf(__fdividef(sa, sp));  // log(sa)-log(sp); fixed max M cancels
            ++cnt;
        }
    }
    #pragma unroll
    for (int off = 32; off; off >>= 1) {
        sum += __shfl_xor(sum, off);
        cnt += __shfl_xor(cnt, off);
    }
    __shared__ float ssum[16];
    __shared__ int scnt[16];
    const int wave = tid >> 6, lane = tid & 63;
    if (lane == 0) { ssum[wave] = sum; scnt[wave] = cnt; }
    __syncthreads();
    if (tid == 0) {
        float s = 0.0f;
        int c = 0;
        #pragma unroll
        for (int w = 0; w < 16; ++w) { s += ssum[w]; c += scnt[w]; }
        out[0] = (c > 0) ? s / (float)c : 0.0f;
    }
}

extern "C" void kernel_launch(void* const* d_in, const int* in_sizes, int n_in,
                              void* d_out, int out_size, void* d_ws, size_t ws_size,
                              hipStream_t stream) {
    const float* emb   = (const float*)d_in[0];
    const int* labels  = (const int*)d_in[1];
    float* out         = (float*)d_out;

    unsigned short* ebf = (unsigned short*)d_ws;                       // 4 MB bf16 normalized
    float* Sall = (float*)((char*)d_ws + (size_t)B_ROWS * DIM * 2);    // 32 KB
    float* Spos = Sall + B_ROWS;                                       // 32 KB

    normalize_k<<<B_ROWS / 4, 256, 0, stream>>>(emb, ebf, Sall);

    dim3 grid((B_ROWS / ROWS_PER_BLOCK) * (B_ROWS / JCHUNK));          // 32*16 = 512
    sim_k<<<grid, 256, 0, stream>>>(ebf, labels, Sall, Spos);

    finalize_k<<<1, 1024, 0, stream>>>(Sall, Spos, out);
}